// Round 4
// baseline (47.858 us; speedup 1.0000x reference)
//
#include <hip/hip_runtime.h>

// out[b,k] = sum_n exp(-2*pi * ||dom_k - C[b,n]||^2)
//   e = S1*(dom_k . c_n) - S2*||c_n||^2 - S2*||dom_k||^2,  S2 = 2*pi/ln2
//   value = exp2(e) via v_exp_f32.
// R4: LDS-DS-pipe fix. One ds_read_b128 (atom {x,y,z,w}) now feeds 8 k's
// (4 packed k-pairs): 16 v_pk_fma/pk_add + 8 exps per read. Atom coords are
// broadcast inside VOP3P via op_sel/op_sel_hi (no splat movs). Per-CU DS load
// drops 4x below the trans-pipe floor (~13.7 us).
// Grid: 4 k-tiles x 32 b x 4 atom-quarters = 512 blocks x 512 thr;
// block partials combined with f32 atomicAdd after async memset.

#define NATOMS  4096
#define K_TOTAL 2048
#define KTILE   512             // k per block (each wave covers all 512)
#define BLOCK   512             // 8 waves
#define NWAVES  8
#define QATOMS  1024            // atoms per block (quarter of NATOMS)
#define APT     (QATOMS / NWAVES) // atom iters per thread = 128

typedef float f2 __attribute__((ext_vector_type(2)));
typedef float f4 __attribute__((ext_vector_type(4)));

#if defined(__has_builtin)
#if __has_builtin(__builtin_amdgcn_exp2f)
#define HAVE_EXP2_BUILTIN 1
#endif
#endif

__device__ __forceinline__ float fast_exp2(float x) {
#ifdef HAVE_EXP2_BUILTIN
    return __builtin_amdgcn_exp2f(x);
#else
    float r;
    asm("v_exp_f32 %0, %1" : "=v"(r) : "v"(x));
    return r;
#endif
}

// VOP3P packed f32 with word-broadcast of source-0:
//   lo result uses op_sel[i] word of src i, hi result uses op_sel_hi[i] word.
__device__ __forceinline__ f2 pk_fma_bx(f2 a, f2 b, f2 c) { // a.x * b + c
    f2 d;
    asm("v_pk_fma_f32 %0, %1, %2, %3 op_sel_hi:[0,1,1]"
        : "=v"(d) : "v"(a), "v"(b), "v"(c));
    return d;
}
__device__ __forceinline__ f2 pk_fma_by(f2 a, f2 b, f2 c) { // a.y * b + c
    f2 d;
    asm("v_pk_fma_f32 %0, %1, %2, %3 op_sel:[1,0,0] op_sel_hi:[1,1,1]"
        : "=v"(d) : "v"(a), "v"(b), "v"(c));
    return d;
}
__device__ __forceinline__ f2 pk_add_by(f2 a, f2 b) {       // a.y + b
    f2 d;
    asm("v_pk_add_f32 %0, %1, %2 op_sel:[1,0] op_sel_hi:[1,1]"
        : "=v"(d) : "v"(a), "v"(b));
    return d;
}

__global__ __launch_bounds__(BLOCK) void theta_layer_kernel(
        const float* __restrict__ C, const float* __restrict__ dom,
        float* __restrict__ out) {
    constexpr float S2 = 9.064720283654388f;   // 2*pi / ln(2)
    constexpr float S1 = 18.129440567308776f;  // 4*pi / ln(2)

    __shared__ f4 sA[QATOMS];  // 16 KB: {x,y,z,-S2*||c||^2}; reused for reduce

    const int tid  = threadIdx.x;
    const int lane = tid & 63;
    const int w    = tid >> 6;
    const int b    = blockIdx.y;
    const int kt   = blockIdx.x >> 2;   // 0..3 k-tile
    const int q    = blockIdx.x & 3;    // 0..3 atom quarter
    const int Kb   = kt * KTILE;

    // ---- stage this quarter's atoms into LDS ----
    const float* Cq = C + ((size_t)b * NATOMS + (size_t)q * QATOMS) * 3;
    for (int j = tid; j < QATOMS; j += BLOCK) {
        float x = Cq[3 * j + 0];
        float y = Cq[3 * j + 1];
        float z = Cq[3 * j + 2];
        f4 v = {x, y, z, -S2 * (x * x + y * y + z * z)};
        sA[j] = v;
    }

    // ---- per-thread k constants: 4 k-pairs (8 k's) ----
    f2 xk[4], yk[4], zk[4], dk[4];
    #pragma unroll
    for (int p = 0; p < 4; ++p) {
        const int k0 = Kb + 2 * (p * 64 + lane);
        const float dx0 = dom[3 * k0 + 0], dy0 = dom[3 * k0 + 1], dz0 = dom[3 * k0 + 2];
        const float dx1 = dom[3 * k0 + 3], dy1 = dom[3 * k0 + 4], dz1 = dom[3 * k0 + 5];
        xk[p] = f2{S1 * dx0, S1 * dx1};
        yk[p] = f2{S1 * dy0, S1 * dy1};
        zk[p] = f2{S1 * dz0, S1 * dz1};
        dk[p] = f2{-S2 * (dx0 * dx0 + dy0 * dy0 + dz0 * dz0),
                   -S2 * (dx1 * dx1 + dy1 * dy1 + dz1 * dz1)};
    }

    __syncthreads();

    // ---- main loop: 1 ds_read_b128 -> 16 packed VALU + 8 exp ----
    f2 acc[4];
    #pragma unroll
    for (int p = 0; p < 4; ++p) acc[p] = f2{0.f, 0.f};

    const f4* pa = sA + w * APT;
    #pragma unroll 2
    for (int j = 0; j < APT; ++j) {
        f4 a  = pa[j];                                   // broadcast read
        f2 xy = __builtin_shufflevector(a, a, 0, 1);     // {x,y}
        f2 zw = __builtin_shufflevector(a, a, 2, 3);     // {z,w}
        #pragma unroll
        for (int p = 0; p < 4; ++p) {
            f2 t = pk_fma_bx(xy, xk[p], dk[p]);          // x*xk + dk
            t    = pk_fma_by(xy, yk[p], t);              // + y*yk
            t    = pk_fma_bx(zw, zk[p], t);              // + z*zk
            t    = pk_add_by(zw, t);                     // + w
            acc[p].x += fast_exp2(t.x);
            acc[p].y += fast_exp2(t.y);
        }
    }

    // ---- block reduce over 8 waves (reuse sA as f2 red[NWAVES][256]) ----
    __syncthreads();
    f2* red = (f2*)sA;
    #pragma unroll
    for (int p = 0; p < 4; ++p) red[w * 256 + p * 64 + lane] = acc[p];
    __syncthreads();

    if (tid < 256) {
        f2 s = f2{0.f, 0.f};
        #pragma unroll
        for (int w2 = 0; w2 < NWAVES; ++w2) {
            f2 r = red[w2 * 256 + tid];
            s.x += r.x;
            s.y += r.y;
        }
        float* o = out + (size_t)b * K_TOTAL + Kb + 2 * tid;
        atomicAdd(o + 0, s.x);
        atomicAdd(o + 1, s.y);
    }
}

extern "C" void kernel_launch(void* const* d_in, const int* in_sizes, int n_in,
                              void* d_out, int out_size, void* d_ws, size_t ws_size,
                              hipStream_t stream) {
    const float* C   = (const float*)d_in[0];
    const float* dom = (const float*)d_in[1];
    float* out       = (float*)d_out;
    const int B = in_sizes[0] / (NATOMS * 3);  // 32
    hipMemsetAsync(out, 0, (size_t)out_size * sizeof(float), stream);
    dim3 grid(16, B);  // (4 k-tiles x 4 atom-quarters) x B
    theta_layer_kernel<<<grid, BLOCK, 0, stream>>>(C, dom, out);
}

// Round 5
// 33.097 us; speedup vs baseline: 1.4460x; 1.4460x over previous
//
#include <hip/hip_runtime.h>

// out[b,k] = sum_n exp(-2*pi*||dom_k - C[b,n]||^2)
//   e = px*x + py*y + pz*z + wn + dk   (base-2 exponent, p = S1*d)
//   wn = -S2*||c||^2, dk = -S2*||d||^2, S2 = 2*pi/ln2, S1 = 2*S2
// R5: offload the bilinear form to MFMA (v_mfma_f32_32x32x16_bf16) using a
// split-bf16 encoding across the K=16 dim (hi*hi + lo*hi + hi*lo in ONE mfma):
//   K0-4 : A={xh,yh,zh,wh,1}    B={pxh,pyh,pzh,1,dkh}
//   K5-8 : A={xl,yl,zl,wl}      B={pxh,pyh,pzh,1}
//   K9-12: A={1,xh,yh,zh}       B={dkl,pxl,pyl,pzl}
// One MFMA = 32k x 32n exponent tile; VALU does only 16 exp + 16 adds.
// Grid: 32 b x 8 k-groups x 2 atom-halves = 512 blocks x 512 thr.

#define NATOMS 4096
#define KTOT   2048
#define BLOCK  512
#define ATILES 64      // 32-atom tiles per block (2048 atoms)
#define AHALF  2048

typedef float  f32x16 __attribute__((ext_vector_type(16)));
typedef __bf16 bf16x8 __attribute__((ext_vector_type(8)));

__device__ __forceinline__ float fast_exp2(float x) {
    return __builtin_amdgcn_exp2f(x);
}

__global__ __launch_bounds__(BLOCK) void theta_layer_kernel(
        const float* __restrict__ C, const float* __restrict__ dom,
        float* __restrict__ out) {
    constexpr float S2 = 9.064720283654388f;   // 2*pi / ln(2)
    constexpr float S1 = 18.129440567308776f;  // 4*pi / ln(2)

    // Prepacked A-fragments: tile t, frag-lane l -> 8 bf16 (16B). 64 KB.
    __shared__ bf16x8 sA[ATILES * 64];

    const int tid  = threadIdx.x;
    const int lane = tid & 63;
    const int w    = tid >> 6;        // wave 0..7
    const int b    = blockIdx.y;
    const int kg   = blockIdx.x & 7;  // k-group (8 k-tiles each)
    const int q    = blockIdx.x >> 3; // atom half 0/1

    const __bf16 one = (__bf16)1.0f;
    const __bf16 zb  = (__bf16)0.0f;

    // ---- stage atom A-fragments into LDS ----
    const float* Cb = C + ((size_t)b * NATOMS + (size_t)q * AHALF) * 3;
    for (int j = tid; j < AHALF; j += BLOCK) {
        float x = Cb[3 * j + 0];
        float y = Cb[3 * j + 1];
        float z = Cb[3 * j + 2];
        __bf16 xh = (__bf16)x; __bf16 xl = (__bf16)(x - (float)xh);
        __bf16 yh = (__bf16)y; __bf16 yl = (__bf16)(y - (float)yh);
        __bf16 zh = (__bf16)z; __bf16 zl = (__bf16)(z - (float)zh);
        float wn = -S2 * (x * x + y * y + z * z);
        __bf16 wh = (__bf16)wn; __bf16 wl = (__bf16)(wn - (float)wh);
        const int t = j >> 5, r = j & 31;
        bf16x8 f0 = {xh, yh, zh, wh, one, xl, yl, zl};  // K0-7  (lanes 0-31)
        bf16x8 f1 = {wl, one, xh, yh, zh, zb, zb, zb};  // K8-15 (lanes 32-63)
        sA[t * 64 + r]      = f0;
        sA[t * 64 + 32 + r] = f1;
    }

    // ---- per-wave B fragment (dom side), col k = lane&31 of this k-tile ----
    const int kt = kg * 8 + w;                 // k-tile 0..63
    const int k  = kt * 32 + (lane & 31);
    const float dx = dom[3 * k + 0], dy = dom[3 * k + 1], dz = dom[3 * k + 2];
    const float px = S1 * dx, py = S1 * dy, pz = S1 * dz;
    __bf16 pxh = (__bf16)px; __bf16 pxl = (__bf16)(px - (float)pxh);
    __bf16 pyh = (__bf16)py; __bf16 pyl = (__bf16)(py - (float)pyh);
    __bf16 pzh = (__bf16)pz; __bf16 pzl = (__bf16)(pz - (float)pzh);
    const float dkf = -S2 * (dx * dx + dy * dy + dz * dz);
    __bf16 dkh = (__bf16)dkf; __bf16 dkl = (__bf16)(dkf - (float)dkh);

    bf16x8 bfrag;
    if (lane < 32) {
        bf16x8 t0 = {pxh, pyh, pzh, one, dkh, pxh, pyh, pzh};  // K0-7
        bfrag = t0;
    } else {
        bf16x8 t1 = {one, dkl, pxl, pyl, pzl, zb, zb, zb};     // K8-15
        bfrag = t1;
    }

    __syncthreads();

    // ---- main loop: 1 ds_read_b128 + 1 mfma -> 16 exp + 16 add ----
    const f32x16 zero = {};
    float a0 = 0.f, a1 = 0.f, a2 = 0.f, a3 = 0.f;
    #pragma unroll 2
    for (int t = 0; t < ATILES; ++t) {
        bf16x8 af = sA[t * 64 + lane];
        f32x16 d = __builtin_amdgcn_mfma_f32_32x32x16_bf16(af, bfrag, zero, 0, 0, 0);
        a0 += fast_exp2(d[0]);  a0 += fast_exp2(d[1]);
        a0 += fast_exp2(d[2]);  a0 += fast_exp2(d[3]);
        a1 += fast_exp2(d[4]);  a1 += fast_exp2(d[5]);
        a1 += fast_exp2(d[6]);  a1 += fast_exp2(d[7]);
        a2 += fast_exp2(d[8]);  a2 += fast_exp2(d[9]);
        a2 += fast_exp2(d[10]); a2 += fast_exp2(d[11]);
        a3 += fast_exp2(d[12]); a3 += fast_exp2(d[13]);
        a3 += fast_exp2(d[14]); a3 += fast_exp2(d[15]);
    }
    float acc = (a0 + a1) + (a2 + a3);

    // ---- combine row-halves (lane ^ 32) and emit ----
    float other = __shfl_xor(acc, 32, 64);
    float tot = acc + other;
    if (lane < 32) {
        atomicAdd(&out[(size_t)b * KTOT + k], tot);
    }
}

extern "C" void kernel_launch(void* const* d_in, const int* in_sizes, int n_in,
                              void* d_out, int out_size, void* d_ws, size_t ws_size,
                              hipStream_t stream) {
    const float* C   = (const float*)d_in[0];
    const float* dom = (const float*)d_in[1];
    float* out       = (float*)d_out;
    const int B = in_sizes[0] / (NATOMS * 3);  // 32
    hipMemsetAsync(out, 0, (size_t)out_size * sizeof(float), stream);
    dim3 grid(16, B);  // (8 k-groups x 2 atom-halves) x B
    theta_layer_kernel<<<grid, BLOCK, 0, stream>>>(C, dom, out);
}